// Round 1
// baseline (2195.264 us; speedup 1.0000x reference)
//
#include <hip/hip_runtime.h>
#include <hip/hip_bf16.h>
#include <math.h>

// Transformer block: LN1 -> per-head QKV (full E=768 head dim) -> causal attn
// -> concat -> c_proj + resid(x_norm) -> LN2 -> GELU MLP -> + y2.
// All GEMMs: bf16 inputs, fp32 MFMA accumulate (16x16x32), NT layout (B pre-transposed).

#define BM 128
#define BN 128
#define BK 32

typedef __attribute__((ext_vector_type(8))) short bf16x8;
typedef __attribute__((ext_vector_type(4))) float floatx4;

__device__ __forceinline__ short f2b(float f) {
  __hip_bfloat16 h = __float2bfloat16(f);
  return *reinterpret_cast<short*>(&h);
}
__device__ __forceinline__ float b2f(short s) {
  unsigned u = ((unsigned)(unsigned short)s) << 16;
  return __uint_as_float(u);
}

// MODE 0: Cb = bf16(acc*alpha + bias)                (plain store; causal==1 skips upper tiles, causal==2 limits K)
// MODE 1: transposed store for V: vT[(z*4 + row>>10)*768 + col][row&1023]
// MODE 2: v = acc + bias + resid; Cf = v (fp32); optional Cb = bf16(v)
// MODE 3: Cb = bf16(gelu_exact(acc + bias))
template<int MODE>
__global__ void __launch_bounds__(256) gemm_kernel(
    const short* __restrict__ A, int lda, long a_bs,
    const short* __restrict__ Bt, int ldb, long b_bs,
    const float* __restrict__ bias, int bias_bs,
    short* __restrict__ Cb, int ldc, int zmod, long cz0, long cz1,
    float* __restrict__ Cf, const float* __restrict__ resid,
    int K, float alpha, int causal)
{
  const int m0 = blockIdx.y * BM, n0 = blockIdx.x * BN;
  if (causal == 1 && n0 > m0 + (BM - 1)) return;  // strictly-above-diagonal tile
  const int z = blockIdx.z;
  A  += (size_t)z * a_bs;
  Bt += (size_t)z * b_bs;
  if (bias) bias += (size_t)z * bias_bs;
  const long coff = (long)(z % zmod) * cz0 + (long)(z / zmod) * cz1;
  const int Keff = (causal == 2) ? min(K, m0 + BM) : K;

  __shared__ short As[BM][BK + 8];  // +8 bf16 pad: rows stay 16B aligned, breaks pow2 bank stride
  __shared__ short Bs[BN][BK + 8];

  const int tid = threadIdx.x;
  const int lane = tid & 63;
  const int wave = tid >> 6;
  const int wm = (wave >> 1) * 64;
  const int wn = (wave & 1) * 64;
  const int l15 = lane & 15;
  const int quad = lane >> 4;

  floatx4 acc[4][4];
  const floatx4 zero = {0.0f, 0.0f, 0.0f, 0.0f};
#pragma unroll
  for (int i = 0; i < 4; i++)
#pragma unroll
    for (int j = 0; j < 4; j++) acc[i][j] = zero;

  const int row0 = tid >> 2;        // 0..63
  const int kk0 = (tid & 3) * 8;    // 0,8,16,24

  for (int k0 = 0; k0 < Keff; k0 += BK) {
#pragma unroll
    for (int s = 0; s < 2; s++) {   // 256 threads stage 128x32 A and 128x32 B (16B each slot)
      int row = row0 + s * 64;
      *(int4*)&As[row][kk0] = *(const int4*)&A[(size_t)(m0 + row) * lda + k0 + kk0];
      *(int4*)&Bs[row][kk0] = *(const int4*)&Bt[(size_t)(n0 + row) * ldb + k0 + kk0];
    }
    __syncthreads();
    bf16x8 fa[4], fb[4];
#pragma unroll
    for (int i = 0; i < 4; i++) {
      fa[i] = *(const bf16x8*)&As[wm + i * 16 + l15][quad * 8];  // A[m=l15][k=quad*8+j]
      fb[i] = *(const bf16x8*)&Bs[wn + i * 16 + l15][quad * 8];  // B[k][n=l15] from Bt
    }
#pragma unroll
    for (int i = 0; i < 4; i++)
#pragma unroll
      for (int j = 0; j < 4; j++)
        acc[i][j] = __builtin_amdgcn_mfma_f32_16x16x32_bf16(fa[i], fb[j], acc[i][j], 0, 0, 0);
    __syncthreads();
  }

  // C/D layout (m89-verified): col = lane&15, row = quad*4 + reg
#pragma unroll
  for (int j = 0; j < 4; j++) {
    const int col = n0 + wn + j * 16 + l15;
    const float bvv = bias ? bias[col] : 0.0f;
#pragma unroll
    for (int i = 0; i < 4; i++) {
      const int rb = m0 + wm + i * 16 + quad * 4;
      if (MODE == 0) {
#pragma unroll
        for (int r = 0; r < 4; r++)
          Cb[coff + (size_t)(rb + r) * ldc + col] = f2b(acc[i][j][r] * alpha + bvv);
      } else if (MODE == 1) {
        short4 pk;
        pk.x = f2b(acc[i][j][0] + bvv);
        pk.y = f2b(acc[i][j][1] + bvv);
        pk.z = f2b(acc[i][j][2] + bvv);
        pk.w = f2b(acc[i][j][3] + bvv);
        size_t addr = ((size_t)(z * 4 + (rb >> 10)) * 768 + col) * 1024 + (rb & 1023);
        *(short4*)&Cb[addr] = pk;
      } else if (MODE == 2) {
#pragma unroll
        for (int r = 0; r < 4; r++) {
          size_t idx = (size_t)coff + (size_t)(rb + r) * ldc + col;
          float v = acc[i][j][r] + bvv + resid[idx];
          Cf[idx] = v;
          if (Cb) Cb[idx] = f2b(v);
        }
      } else {
#pragma unroll
        for (int r = 0; r < 4; r++) {
          float t = acc[i][j][r] + bvv;
          float v = 0.5f * t * (1.0f + erff(t * 0.7071067811865475f));
          Cb[coff + (size_t)(rb + r) * ldc + col] = f2b(v);
        }
      }
    }
  }
}

__global__ void __launch_bounds__(256) ln_kernel(
    const float* __restrict__ in, const float* __restrict__ g, const float* __restrict__ b,
    float* __restrict__ outf, short* __restrict__ outb)
{
  const long r = blockIdx.x;
  const float* x = in + r * 768;
  const int tid = threadIdx.x;
  float v0 = x[tid], v1 = x[tid + 256], v2 = x[tid + 512];
  float s = v0 + v1 + v2;
  float sq = v0 * v0 + v1 * v1 + v2 * v2;
  __shared__ float red[8];
  int lane = tid & 63, wave = tid >> 6;
#pragma unroll
  for (int o = 1; o < 64; o <<= 1) { s += __shfl_xor(s, o); sq += __shfl_xor(sq, o); }
  if (lane == 0) { red[wave] = s; red[4 + wave] = sq; }
  __syncthreads();
  s = red[0] + red[1] + red[2] + red[3];
  sq = red[4] + red[5] + red[6] + red[7];
  float mean = s * (1.0f / 768.0f);
  float var = sq * (1.0f / 768.0f) - mean * mean;
  float inv = rsqrtf(var + 1e-5f);
#pragma unroll
  for (int u = 0; u < 3; u++) {
    int c = tid + u * 256;
    float v = (u == 0) ? v0 : ((u == 1) ? v1 : v2);
    float y = (v - mean) * inv * g[c] + b[c];
    outf[r * 768 + c] = y;
    outb[r * 768 + c] = f2b(y);
  }
}

// In-place causal softmax on bf16 scores [batch][1024][1024]; zero-fills (i, i|127]
// so the PV GEMM (K limited to m0+128) reads only defined values.
__global__ void __launch_bounds__(256) softmax_kernel(short* __restrict__ sc)
{
  const long gr = blockIdx.x;
  const int i = (int)(gr & 1023);
  short* row = sc + (gr >> 10) * (1024L * 1024) + (long)i * 1024;
  const int L = i + 1;
  const int tid = threadIdx.x;
  const int lane = tid & 63, wave = tid >> 6;
  __shared__ float red[4];
  float v[4];
  float mx = -3.0e38f;
#pragma unroll
  for (int s = 0; s < 4; s++) {
    int j = tid + s * 256;
    v[s] = (j < L) ? b2f(row[j]) : -3.0e38f;
    mx = fmaxf(mx, v[s]);
  }
#pragma unroll
  for (int o = 1; o < 64; o <<= 1) mx = fmaxf(mx, __shfl_xor(mx, o));
  if (lane == 0) red[wave] = mx;
  __syncthreads();
  mx = fmaxf(fmaxf(red[0], red[1]), fmaxf(red[2], red[3]));
  __syncthreads();
  float sum = 0.0f;
#pragma unroll
  for (int s = 0; s < 4; s++) {
    int j = tid + s * 256;
    if (j < L) { v[s] = __expf(v[s] - mx); sum += v[s]; }
  }
#pragma unroll
  for (int o = 1; o < 64; o <<= 1) sum += __shfl_xor(sum, o);
  if (lane == 0) red[wave] = sum;
  __syncthreads();
  sum = red[0] + red[1] + red[2] + red[3];
  float inv = 1.0f / sum;
#pragma unroll
  for (int s = 0; s < 4; s++) {
    int j = tid + s * 256;
    if (j < L) row[j] = f2b(v[s] * inv);
  }
  const int hi = i | 127;
  for (int j = L + tid; j <= hi; j += 256) row[j] = 0;
}

// W[R][C] fp32 -> Wt[C][R] bf16 (per blockIdx.z batch of R*C)
__global__ void __launch_bounds__(256) transpose_kernel(
    const float* __restrict__ W, short* __restrict__ Wt, int R, int C)
{
  __shared__ float tile[32][33];
  const int c0 = blockIdx.x * 32, r0 = blockIdx.y * 32;
  const size_t zo = (size_t)blockIdx.z * R * C;
  const int tx = threadIdx.x, ty = threadIdx.y;
#pragma unroll
  for (int i = 0; i < 32; i += 8)
    tile[ty + i][tx] = W[zo + (size_t)(r0 + ty + i) * C + (c0 + tx)];
  __syncthreads();
#pragma unroll
  for (int i = 0; i < 32; i += 8)
    Wt[zo + (size_t)(c0 + ty + i) * R + (r0 + tx)] = f2b(tile[tx][ty + i]);
}

extern "C" void kernel_launch(void* const* d_in, const int* in_sizes, int n_in,
                              void* d_out, int out_size, void* d_ws, size_t ws_size,
                              hipStream_t stream)
{
  (void)in_sizes; (void)n_in; (void)out_size;
  const float* inputs = (const float*)d_in[0];
  const float* g1  = (const float*)d_in[1];
  const float* b1  = (const float*)d_in[2];
  const float* Wq  = (const float*)d_in[3];
  const float* bq  = (const float*)d_in[4];
  const float* Wk  = (const float*)d_in[5];
  const float* bk  = (const float*)d_in[6];
  const float* Wv  = (const float*)d_in[7];
  const float* bv  = (const float*)d_in[8];
  const float* Wc  = (const float*)d_in[9];
  const float* bc  = (const float*)d_in[10];
  const float* g2  = (const float*)d_in[11];
  const float* b2  = (const float*)d_in[12];
  const float* Wfc = (const float*)d_in[13];
  const float* bfc = (const float*)d_in[14];
  const float* Wp  = (const float*)d_in[15];
  const float* bp  = (const float*)d_in[16];
  float* out = (float*)d_out;

  const size_t NS = 4096, E = 768, S = 1024, FE = 3072, HE = 9216;

  char* p = (char*)d_ws;
  auto alloc = [&](size_t n) { char* r = p; p += (n + 255) & ~(size_t)255; return r; };

  float* x_f  = (float*)alloc(NS * E * 4);
  short* x_b  = (short*)alloc(NS * E * 2);
  short* WqT  = (short*)alloc(12 * E * E * 2);
  short* WkT  = (short*)alloc(12 * E * E * 2);
  short* WvT  = (short*)alloc(12 * E * E * 2);
  short* WcT  = (short*)alloc(HE * E * 2);
  short* WfcT = (short*)alloc(E * FE * 2);
  short* WpT  = (short*)alloc(FE * E * 2);
  short* cat  = (short*)alloc(NS * HE * 2);
  float* y_f  = (float*)alloc(NS * E * 4);
  float* y2_f = (float*)alloc(NS * E * 4);
  short* y2_b = (short*)alloc(NS * E * 2);
  short* h_b  = (short*)alloc(NS * FE * 2);

  // All-heads pass (HB=12) needs ~533 MB total; per-head fallback (HB=1) ~232 MB.
  size_t fixed_used = (size_t)(p - (char*)d_ws);
  size_t per_h = 3 * (NS * E * 2 + 256) + (4 * S * S * 2 + 256);
  int HB = (ws_size >= fixed_used + 12 * per_h) ? 12 : 1;

  short* q_b = (short*)alloc((size_t)HB * NS * E * 2);
  short* k_b = (short*)alloc((size_t)HB * NS * E * 2);
  short* vT  = (short*)alloc((size_t)HB * NS * E * 2);
  short* sc  = (short*)alloc((size_t)HB * 4 * S * S * 2);

  const dim3 tb(32, 8);
  transpose_kernel<<<dim3(24, 24, 12), tb, 0, stream>>>(Wq, WqT, 768, 768);
  transpose_kernel<<<dim3(24, 24, 12), tb, 0, stream>>>(Wk, WkT, 768, 768);
  transpose_kernel<<<dim3(24, 24, 12), tb, 0, stream>>>(Wv, WvT, 768, 768);
  transpose_kernel<<<dim3(24, 288, 1), tb, 0, stream>>>(Wc, WcT, 9216, 768);
  transpose_kernel<<<dim3(96, 24, 1), tb, 0, stream>>>(Wfc, WfcT, 768, 3072);
  transpose_kernel<<<dim3(24, 96, 1), tb, 0, stream>>>(Wp, WpT, 3072, 768);

  ln_kernel<<<4096, 256, 0, stream>>>(inputs, g1, b1, x_f, x_b);

  const float sca = 0.03608439182435161f;  // 1/sqrt(768)
  for (int h0 = 0; h0 < 12; h0 += HB) {
    // Q, K projections -> bf16 [h][4096][768]
    gemm_kernel<0><<<dim3(6, 32, HB), 256, 0, stream>>>(
        x_b, 768, 0, WqT + (size_t)h0 * E * E, 768, (long)(E * E), bq + h0 * E, (int)E,
        q_b, 768, 1 << 30, (long)(NS * E), 0, nullptr, nullptr, 768, 1.0f, 0);
    gemm_kernel<0><<<dim3(6, 32, HB), 256, 0, stream>>>(
        x_b, 768, 0, WkT + (size_t)h0 * E * E, 768, (long)(E * E), bk + h0 * E, (int)E,
        k_b, 768, 1 << 30, (long)(NS * E), 0, nullptr, nullptr, 768, 1.0f, 0);
    // V projection, stored transposed: vT[(h*4+n)][768][1024]
    gemm_kernel<1><<<dim3(6, 32, HB), 256, 0, stream>>>(
        x_b, 768, 0, WvT + (size_t)h0 * E * E, 768, (long)(E * E), bv + h0 * E, (int)E,
        vT, 0, 1, 0, 0, nullptr, nullptr, 768, 1.0f, 0);
    // scores = q @ k^T / sqrt(E), causal tile skip, bf16 out
    gemm_kernel<0><<<dim3(8, 8, HB * 4), 256, 0, stream>>>(
        q_b, 768, (long)(S * E), k_b, 768, (long)(S * E), nullptr, 0,
        sc, 1024, 1 << 30, (long)(S * S), 0, nullptr, nullptr, 768, sca, 1);
    softmax_kernel<<<HB * 4 * 1024, 256, 0, stream>>>(sc);
    // heads = attn @ v, written directly into concat layout; K limited by causality
    gemm_kernel<0><<<dim3(6, 8, HB * 4), 256, 0, stream>>>(
        sc, 1024, (long)(S * S), vT, 1024, (long)(E * S), nullptr, 0,
        cat + (size_t)h0 * E, 9216, 4, (long)(S * HE), (long)E, nullptr, nullptr, 1024, 1.0f, 2);
  }

  // c_proj: y = cat @ Wc + bc + x_norm (fp32)
  gemm_kernel<2><<<dim3(6, 32, 1), 256, 0, stream>>>(
      cat, 9216, 0, WcT, 9216, 0, bc, 0,
      nullptr, 768, 1, 0, 0, y_f, x_f, 9216, 1.0f, 0);

  ln_kernel<<<4096, 256, 0, stream>>>(y_f, g2, b2, y2_f, y2_b);

  // fc + exact gelu -> bf16 h
  gemm_kernel<3><<<dim3(24, 32, 1), 256, 0, stream>>>(
      y2_b, 768, 0, WfcT, 768, 0, bfc, 0,
      h_b, 3072, 1, 0, 0, nullptr, nullptr, 768, 1.0f, 0);

  // proj + resid(y2) -> fp32 d_out
  gemm_kernel<2><<<dim3(6, 32, 1), 256, 0, stream>>>(
      h_b, 3072, 0, WpT, 3072, 0, bp, 0,
      nullptr, 768, 1, 0, 0, out, y2_f, 3072, 1.0f, 0);
}

// Round 2
// 1350.599 us; speedup vs baseline: 1.6254x; 1.6254x over previous
//
#include <hip/hip_runtime.h>
#include <hip/hip_bf16.h>
#include <math.h>

// Transformer block on gfx950. bf16 MFMA GEMMs (16x16x32), fp32 accumulate.
// Round-2 changes: global_load_lds width-16 staging with swizzled LDS layout
// (2-way-only bank access), merged QKV GEMM (N=2304), split-K=3 c_proj/proj
// with fp32 partials + reduce, adaptive head-group batching within ws_size.

#define BM 128
#define BN 128
#define BK 32

typedef __attribute__((ext_vector_type(8))) short bf16x8;
typedef __attribute__((ext_vector_type(4))) float floatx4;

__device__ __forceinline__ short f2b(float f) {
  __hip_bfloat16 h = __float2bfloat16(f);
  return *reinterpret_cast<short*>(&h);
}
__device__ __forceinline__ float b2f(short s) {
  unsigned u = ((unsigned)(unsigned short)s) << 16;
  return __uint_as_float(u);
}

#if defined(__has_builtin)
#if __has_builtin(__builtin_amdgcn_global_load_lds)
#define HAS_GLLD 1
#endif
#endif

#ifdef HAS_GLLD
__device__ __forceinline__ void lds_dma16(const short* g, short* l) {
  // HW semantics: LDS dest = wave-uniform base + lane*16B (we pass uniform base).
  __builtin_amdgcn_global_load_lds(
      (const __attribute__((address_space(1))) void*)g,
      (__attribute__((address_space(3))) void*)l, 16, 0, 0);
}
#endif

struct GP {
  const short* A; const short* B;
  long a_bs, b_bs;
  int lda, ldb;
  int a_kh; long a_hs;          // if a_kh>0: A addr = (k/a_kh)*a_hs + row*lda + k%a_kh
  const float* bias0; const float* bias1; const float* bias2;
  short* C0; short* C1; short* C2;
  float* Cf;
  int ldc, zmod;
  long cz0, cz1, c_zs;
  int K, kchunk;                // kchunk>0: this z handles K range [z*kchunk, +kchunk)
  float alpha;
  int causal, zoff;
};

// MODE 0: C0 = bf16(acc*alpha)            (scores causal=1 tile-skip; PV causal=2 K-limit)
// MODE 3: C0 = bf16(gelu(acc + bias0[col]))
// MODE 4: Cf[z*c_zs + ...] = acc          (split-K fp32 partial)
// MODE 5: QKV routing by column part: q->C0, k->C1, v->C2 (transposed layout)
template<int MODE>
__global__ void __launch_bounds__(256) gemm_kernel(GP p)
{
  const int m0 = blockIdx.y * BM, n0 = blockIdx.x * BN;
  if (p.causal == 1 && n0 > m0 + (BM - 1)) return;
  const int z = blockIdx.z;
  const short* Ab = p.A + (size_t)z * p.a_bs;
  const short* Bb = p.B + (size_t)z * p.b_bs;
  int kbeg = 0, kend = p.K;
  if (p.kchunk) { kbeg = z * p.kchunk; kend = kbeg + p.kchunk; }
  if (p.causal == 2) { int lim = m0 + BM; if (lim < kend) kend = lim; }

  __shared__ __align__(16) short As[BM * BK];   // swizzled: chunk c of row r at pos (c + (r>>1)) & 3
  __shared__ __align__(16) short Bs[BN * BK];

  const int tid = threadIdx.x;
  const int lane = tid & 63, wave = tid >> 6;
  const int wm = (wave >> 1) * 64, wn = (wave & 1) * 64;
  const int l15 = lane & 15, quad = lane >> 4;
  const int rl = lane >> 2, pl = lane & 3;

  floatx4 acc[4][4];
#pragma unroll
  for (int i = 0; i < 4; i++)
#pragma unroll
    for (int j = 0; j < 4; j++) acc[i][j] = (floatx4){0.f, 0.f, 0.f, 0.f};

  for (int k0 = kbeg; k0 < kend; k0 += BK) {
    const short* Ak = Ab; int kb = k0;
    if (p.a_kh) { int h = k0 / p.a_kh; Ak = Ab + (size_t)h * p.a_hs; kb = k0 - h * p.a_kh; }
#pragma unroll
    for (int s = 0; s < 2; s++) {
      const int win = wave * 2 + s;            // 8 windows of 16 rows (1 KB each)
      const int row = win * 16 + rl;
      const int cs = (pl - (row >> 1)) & 3;    // global chunk landing at LDS pos pl
      const short* ga = Ak + (size_t)(m0 + row) * p.lda + kb + cs * 8;
      const short* gb = Bb + (size_t)(n0 + row) * p.ldb + k0 + cs * 8;
#ifdef HAS_GLLD
      lds_dma16(ga, &As[win * 512]);
      lds_dma16(gb, &Bs[win * 512]);
#else
      *(int4*)&As[win * 512 + lane * 8] = *(const int4*)ga;
      *(int4*)&Bs[win * 512 + lane * 8] = *(const int4*)gb;
#endif
    }
    __syncthreads();
    bf16x8 fa[4], fb[4];
#pragma unroll
    for (int i = 0; i < 4; i++) {
      const int ra = wm + i * 16 + l15;
      fa[i] = *(const bf16x8*)&As[ra * 32 + ((quad + (ra >> 1)) & 3) * 8];
      const int rb = wn + i * 16 + l15;
      fb[i] = *(const bf16x8*)&Bs[rb * 32 + ((quad + (rb >> 1)) & 3) * 8];
    }
#pragma unroll
    for (int i = 0; i < 4; i++)
#pragma unroll
      for (int j = 0; j < 4; j++)
        acc[i][j] = __builtin_amdgcn_mfma_f32_16x16x32_bf16(fa[i], fb[j], acc[i][j], 0, 0, 0);
    __syncthreads();
  }

  // C/D layout (m89): col = lane&15, row = quad*4 + reg
  const long coff = (long)(z % p.zmod) * p.cz0 + (long)(z / p.zmod) * p.cz1;
#pragma unroll
  for (int j = 0; j < 4; j++) {
    const int col = n0 + wn + j * 16 + l15;
    if constexpr (MODE == 0) {
#pragma unroll
      for (int i = 0; i < 4; i++) {
        const int rb = m0 + wm + i * 16 + quad * 4;
#pragma unroll
        for (int r = 0; r < 4; r++)
          p.C0[coff + (size_t)(rb + r) * p.ldc + col] = f2b(acc[i][j][r] * p.alpha);
      }
    } else if constexpr (MODE == 5) {
      const int part = (n0 + wn) / 768;        // wave-uniform: 0=q, 1=k, 2=v
      const int cc = col - part * 768;
      const float* bp_ = (part == 0) ? p.bias0 : ((part == 1) ? p.bias1 : p.bias2);
      const float bvv = bp_[(p.zoff + z) * 768 + cc];
      if (part < 2) {
        short* dst = part ? p.C1 : p.C0;
#pragma unroll
        for (int i = 0; i < 4; i++) {
          const int rb = m0 + wm + i * 16 + quad * 4;
#pragma unroll
          for (int r = 0; r < 4; r++)
            dst[(size_t)z * p.c_zs + (size_t)(rb + r) * 768 + cc] = f2b(acc[i][j][r] + bvv);
        }
      } else {
#pragma unroll
        for (int i = 0; i < 4; i++) {
          const int rb = m0 + wm + i * 16 + quad * 4;
          short4 pk;
          pk.x = f2b(acc[i][j][0] + bvv);
          pk.y = f2b(acc[i][j][1] + bvv);
          pk.z = f2b(acc[i][j][2] + bvv);
          pk.w = f2b(acc[i][j][3] + bvv);
          const size_t addr = (((size_t)z * 4 + (rb >> 10)) * 768 + cc) * 1024 + (rb & 1023);
          *(short4*)&p.C2[addr] = pk;
        }
      }
    } else if constexpr (MODE == 4) {
#pragma unroll
      for (int i = 0; i < 4; i++) {
        const int rb = m0 + wm + i * 16 + quad * 4;
#pragma unroll
        for (int r = 0; r < 4; r++)
          p.Cf[(size_t)z * p.c_zs + (size_t)(rb + r) * p.ldc + col] = acc[i][j][r];
      }
    } else {  // MODE 3: exact gelu
      const float bvv = p.bias0[col];
#pragma unroll
      for (int i = 0; i < 4; i++) {
        const int rb = m0 + wm + i * 16 + quad * 4;
#pragma unroll
        for (int r = 0; r < 4; r++) {
          float t = acc[i][j][r] + bvv;
          p.C0[(size_t)(rb + r) * p.ldc + col] = f2b(0.5f * t * (1.0f + erff(t * 0.70710678118654752440f)));
        }
      }
    }
  }
}

__global__ void __launch_bounds__(256) ln_kernel(
    const float* __restrict__ in, const float* __restrict__ g, const float* __restrict__ b,
    float* __restrict__ outf, short* __restrict__ outb)
{
  const long r = blockIdx.x;
  const float* x = in + r * 768;
  const int tid = threadIdx.x;
  float v0 = x[tid], v1 = x[tid + 256], v2 = x[tid + 512];
  float s = v0 + v1 + v2;
  float sq = v0 * v0 + v1 * v1 + v2 * v2;
  __shared__ float red[8];
  int lane = tid & 63, wave = tid >> 6;
#pragma unroll
  for (int o = 1; o < 64; o <<= 1) { s += __shfl_xor(s, o); sq += __shfl_xor(sq, o); }
  if (lane == 0) { red[wave] = s; red[4 + wave] = sq; }
  __syncthreads();
  s = red[0] + red[1] + red[2] + red[3];
  sq = red[4] + red[5] + red[6] + red[7];
  float mean = s * (1.0f / 768.0f);
  float var = sq * (1.0f / 768.0f) - mean * mean;
  float inv = rsqrtf(var + 1e-5f);
#pragma unroll
  for (int u = 0; u < 3; u++) {
    int c = tid + u * 256;
    float v = (u == 0) ? v0 : ((u == 1) ? v1 : v2);
    float y = (v - mean) * inv * g[c] + b[c];
    outf[r * 768 + c] = y;
    outb[r * 768 + c] = f2b(y);
  }
}

__global__ void __launch_bounds__(256) softmax_kernel(short* __restrict__ sc)
{
  const long gr = blockIdx.x;
  const int i = (int)(gr & 1023);
  short* row = sc + (gr >> 10) * (1024L * 1024) + (long)i * 1024;
  const int L = i + 1;
  const int tid = threadIdx.x;
  const int lane = tid & 63, wave = tid >> 6;
  __shared__ float red[4];
  float v[4];
  float mx = -3.0e38f;
#pragma unroll
  for (int s = 0; s < 4; s++) {
    int j = tid + s * 256;
    v[s] = (j < L) ? b2f(row[j]) : -3.0e38f;
    mx = fmaxf(mx, v[s]);
  }
#pragma unroll
  for (int o = 1; o < 64; o <<= 1) mx = fmaxf(mx, __shfl_xor(mx, o));
  if (lane == 0) red[wave] = mx;
  __syncthreads();
  mx = fmaxf(fmaxf(red[0], red[1]), fmaxf(red[2], red[3]));
  __syncthreads();
  float sum = 0.0f;
#pragma unroll
  for (int s = 0; s < 4; s++) {
    int j = tid + s * 256;
    if (j < L) { v[s] = __expf(v[s] - mx); sum += v[s]; }
  }
#pragma unroll
  for (int o = 1; o < 64; o <<= 1) sum += __shfl_xor(sum, o);
  if (lane == 0) red[wave] = sum;
  __syncthreads();
  sum = red[0] + red[1] + red[2] + red[3];
  float inv = 1.0f / sum;
#pragma unroll
  for (int s = 0; s < 4; s++) {
    int j = tid + s * 256;
    if (j < L) row[j] = f2b(v[s] * inv);
  }
  const int hi = i | 127;
  for (int j = L + tid; j <= hi; j += 256) row[j] = 0;
}

__global__ void __launch_bounds__(256) reduce_kernel(
    const float* __restrict__ part, long pzs, int nsplit,
    const float* __restrict__ bias, const float* __restrict__ resid,
    float* __restrict__ out)
{
  const size_t idx = ((size_t)blockIdx.x * 256 + threadIdx.x) * 4;
  float4 s = *(const float4*)&part[idx];
  for (int zz = 1; zz < nsplit; zz++) {
    float4 q = *(const float4*)&part[(size_t)zz * pzs + idx];
    s.x += q.x; s.y += q.y; s.z += q.z; s.w += q.w;
  }
  const int c = (int)(idx % 768);
  float4 b = *(const float4*)&bias[c];
  float4 r = *(const float4*)&resid[idx];
  *(float4*)&out[idx] = make_float4(s.x + b.x + r.x, s.y + b.y + r.y,
                                    s.z + b.z + r.z, s.w + b.w + r.w);
}

// W[R][C] fp32 -> Wt[C][R] bf16, per-z src/dst strides
__global__ void __launch_bounds__(256) transpose_kernel(
    const float* __restrict__ W, short* __restrict__ Wt, int R, int C, long szs, long dzs)
{
  __shared__ float tile[32][33];
  const int c0 = blockIdx.x * 32, r0 = blockIdx.y * 32;
  const float* Wz = W + (size_t)blockIdx.z * szs;
  short* Wtz = Wt + (size_t)blockIdx.z * dzs;
  const int tx = threadIdx.x, ty = threadIdx.y;
#pragma unroll
  for (int i = 0; i < 32; i += 8)
    tile[ty + i][tx] = Wz[(size_t)(r0 + ty + i) * C + (c0 + tx)];
  __syncthreads();
#pragma unroll
  for (int i = 0; i < 32; i += 8)
    Wtz[(size_t)(c0 + ty + i) * R + (r0 + tx)] = f2b(tile[tx][ty + i]);
}

extern "C" void kernel_launch(void* const* d_in, const int* in_sizes, int n_in,
                              void* d_out, int out_size, void* d_ws, size_t ws_size,
                              hipStream_t stream)
{
  (void)in_sizes; (void)n_in; (void)out_size;
  const float* inputs = (const float*)d_in[0];
  const float* g1  = (const float*)d_in[1];
  const float* b1  = (const float*)d_in[2];
  const float* Wq  = (const float*)d_in[3];
  const float* bq  = (const float*)d_in[4];
  const float* Wk  = (const float*)d_in[5];
  const float* bk  = (const float*)d_in[6];
  const float* Wv  = (const float*)d_in[7];
  const float* bv  = (const float*)d_in[8];
  const float* Wc  = (const float*)d_in[9];
  const float* bc  = (const float*)d_in[10];
  const float* g2  = (const float*)d_in[11];
  const float* b2  = (const float*)d_in[12];
  const float* Wfc = (const float*)d_in[13];
  const float* bfc = (const float*)d_in[14];
  const float* Wp  = (const float*)d_in[15];
  const float* bp  = (const float*)d_in[16];
  float* out = (float*)d_out;

  const size_t NS = 4096, E = 768, S = 1024;

  char* base = (char*)d_ws;
  size_t off = 0;
  auto alloc = [&](size_t n) { char* r = base + off; off = (off + n + 255) & ~(size_t)255; return r; };

  float* x_f  = (float*)alloc(NS * E * 4);
  short* x_b  = (short*)alloc(NS * E * 2);
  short* Wqkv = (short*)alloc(12 * 3 * E * E * 2);   // [h][{q,k,v}][768][768] bf16 (B^T)
  short* WcT  = (short*)alloc(E * 9216 * 2);
  short* WfcT = (short*)alloc(3072 * E * 2);
  short* WpT  = (short*)alloc(E * 3072 * 2);
  short* cat  = (short*)alloc(12 * NS * E * 2);      // head-major [h][4096][768]; later proj partial
  float* y_f  = (float*)alloc(NS * E * 4);
  short* h_b  = (short*)alloc(NS * 3072 * 2);        // c_proj partial aliases h_b..y2_f (dead then)
  short* y2_b = (short*)alloc(NS * E * 2);
  float* y2_f = (float*)alloc(NS * E * 4);

  float* partA = (float*)h_b;   // 3*12.6MB fits in h_b+y2_b+y2_f (44MB), all dead during c_proj
  float* partB = (float*)cat;   // cat dead during final proj

  const size_t core = off;
  const size_t per_h = 3 * (NS * E * 2) + 4 * S * S * 2 + 1024;
  static const int Gs[6] = {12, 6, 4, 3, 2, 1};
  int G = 1;
  for (int i = 0; i < 6; i++)
    if (core + (size_t)Gs[i] * per_h <= ws_size) { G = Gs[i]; break; }

  short* q_g  = (short*)alloc((size_t)G * NS * E * 2);
  short* k_g  = (short*)alloc((size_t)G * NS * E * 2);
  short* vT_g = (short*)alloc((size_t)G * NS * E * 2);   // [z*4+n][768][1024]
  short* sc_g = (short*)alloc((size_t)G * 4 * S * S * 2);

  const dim3 tb(32, 8);
  transpose_kernel<<<dim3(24, 24, 12), tb, 0, stream>>>(Wq, Wqkv,             768, 768, (long)(E*E), (long)(3*E*E));
  transpose_kernel<<<dim3(24, 24, 12), tb, 0, stream>>>(Wk, Wqkv + E*E,       768, 768, (long)(E*E), (long)(3*E*E));
  transpose_kernel<<<dim3(24, 24, 12), tb, 0, stream>>>(Wv, Wqkv + 2*E*E,     768, 768, (long)(E*E), (long)(3*E*E));
  transpose_kernel<<<dim3(24, 288, 1), tb, 0, stream>>>(Wc, WcT, 9216, 768, 0, 0);
  transpose_kernel<<<dim3(96, 24, 1),  tb, 0, stream>>>(Wfc, WfcT, 768, 3072, 0, 0);
  transpose_kernel<<<dim3(24, 96, 1),  tb, 0, stream>>>(Wp, WpT, 3072, 768, 0, 0);

  ln_kernel<<<4096, 256, 0, stream>>>(inputs, g1, b1, x_f, x_b);

  const float sca = 0.03608439182435161f;  // 1/sqrt(768)
  for (int h0 = 0; h0 < 12; h0 += G) {
    {  // merged QKV: N = 2304 per head
      GP p{};
      p.A = x_b; p.lda = 768; p.a_bs = 0;
      p.B = Wqkv + (size_t)h0 * 3 * E * E; p.ldb = 768; p.b_bs = (long)(3 * E * E);
      p.bias0 = bq; p.bias1 = bk; p.bias2 = bv; p.zoff = h0;
      p.C0 = q_g; p.C1 = k_g; p.C2 = vT_g; p.c_zs = (long)(NS * E);
      p.ldc = 768; p.zmod = 1;
      p.K = 768; p.alpha = 1.0f;
      gemm_kernel<5><<<dim3(18, 32, G), 256, 0, stream>>>(p);
    }
    {  // scores = q k^T / sqrt(E)
      GP p{};
      p.A = q_g; p.lda = 768; p.a_bs = (long)(S * E);
      p.B = k_g; p.ldb = 768; p.b_bs = (long)(S * E);
      p.C0 = sc_g; p.ldc = 1024; p.zmod = 1; p.cz0 = 0; p.cz1 = (long)(S * S);
      p.K = 768; p.alpha = sca; p.causal = 1;
      gemm_kernel<0><<<dim3(8, 8, 4 * G), 256, 0, stream>>>(p);
    }
    softmax_kernel<<<4 * G * 1024, 256, 0, stream>>>(sc_g);
    {  // heads = attn @ v -> cat[h][4096][768]
      GP p{};
      p.A = sc_g; p.lda = 1024; p.a_bs = (long)(S * S);
      p.B = vT_g; p.ldb = 1024; p.b_bs = (long)(E * S);
      p.C0 = cat + (size_t)h0 * NS * E; p.ldc = 768;
      p.zmod = 4; p.cz0 = (long)(S * E); p.cz1 = (long)(NS * E);
      p.K = 1024; p.alpha = 1.0f; p.causal = 2;
      gemm_kernel<0><<<dim3(6, 8, 4 * G), 256, 0, stream>>>(p);
    }
  }

  {  // c_proj split-K=3 over head-major cat
    GP p{};
    p.A = cat; p.lda = 768; p.a_kh = 768; p.a_hs = (long)(NS * E);
    p.B = WcT; p.ldb = 9216;
    p.Cf = partA; p.ldc = 768; p.c_zs = (long)(NS * E); p.zmod = 1;
    p.K = 9216; p.kchunk = 3072; p.alpha = 1.0f;
    gemm_kernel<4><<<dim3(6, 32, 3), 256, 0, stream>>>(p);
  }
  reduce_kernel<<<3072, 256, 0, stream>>>(partA, (long)(NS * E), 3, bc, x_f, y_f);

  ln_kernel<<<4096, 256, 0, stream>>>(y_f, g2, b2, y2_f, y2_b);

  {  // fc + exact gelu
    GP p{};
    p.A = y2_b; p.lda = 768;
    p.B = WfcT; p.ldb = 768;
    p.bias0 = bfc; p.C0 = h_b; p.ldc = 3072; p.zmod = 1;
    p.K = 768; p.alpha = 1.0f;
    gemm_kernel<3><<<dim3(24, 32, 1), 256, 0, stream>>>(p);
  }
  {  // proj split-K=3
    GP p{};
    p.A = h_b; p.lda = 3072;
    p.B = WpT; p.ldb = 3072;
    p.Cf = partB; p.ldc = 768; p.c_zs = (long)(NS * E); p.zmod = 1;
    p.K = 3072; p.kchunk = 1024; p.alpha = 1.0f;
    gemm_kernel<4><<<dim3(6, 32, 3), 256, 0, stream>>>(p);
  }
  reduce_kernel<<<3072, 256, 0, stream>>>(partB, (long)(NS * E), 3, bp, y2_f, out);
}

// Round 3
// 1009.113 us; speedup vs baseline: 2.1754x; 1.3384x over previous
//
#include <hip/hip_runtime.h>
#include <hip/hip_bf16.h>
#include <math.h>

// Transformer block on gfx950. bf16 MFMA GEMMs (16x16x32), fp32 accumulate.
// Round-3: blockIdx.x = m-tile (divisible by 8) so A-stripe sharers land on the
// same XCD (L2 fill once); split-K=4 c_proj/proj; G=4 head groups via workspace
// overlay; fused reduce+LN2 kernel.

#define BM 128
#define BN 128
#define BK 32

typedef __attribute__((ext_vector_type(8))) short bf16x8;
typedef __attribute__((ext_vector_type(4))) float floatx4;

__device__ __forceinline__ short f2b(float f) {
  __hip_bfloat16 h = __float2bfloat16(f);
  return *reinterpret_cast<short*>(&h);
}
__device__ __forceinline__ float b2f(short s) {
  unsigned u = ((unsigned)(unsigned short)s) << 16;
  return __uint_as_float(u);
}

#if defined(__has_builtin)
#if __has_builtin(__builtin_amdgcn_global_load_lds)
#define HAS_GLLD 1
#endif
#endif

#ifdef HAS_GLLD
__device__ __forceinline__ void lds_dma16(const short* g, short* l) {
  __builtin_amdgcn_global_load_lds(
      (const __attribute__((address_space(1))) void*)g,
      (__attribute__((address_space(3))) void*)l, 16, 0, 0);
}
#endif

struct GP {
  const short* A; const short* B;
  long a_bs, b_bs;
  int lda, ldb;
  int a_kh; long a_hs;          // if a_kh>0: A addr = (k/a_kh)*a_hs + row*lda + k%a_kh
  const float* bias0; const float* bias1; const float* bias2;
  short* C0; short* C1; short* C2;
  float* Cf;
  int ldc, zmod;
  long cz0, cz1, c_zs;
  int K, kchunk;                // kchunk>0: this z handles K range [z*kchunk, +kchunk)
  float alpha;
  int causal, zoff;
};

// MODE 0: C0 = bf16(acc*alpha)            (scores causal=1 tile-skip; PV causal=2 K-limit)
// MODE 3: C0 = bf16(gelu(acc + bias0[col]))
// MODE 4: Cf[z*c_zs + ...] = acc          (split-K fp32 partial)
// MODE 5: QKV routing by column part: q->C0, k->C1, v->C2 (transposed layout)
template<int MODE>
__global__ void __launch_bounds__(256) gemm_kernel(GP p)
{
  const int m0 = blockIdx.x * BM, n0 = blockIdx.y * BN;   // x = m-tile: XCD A-locality
  if (p.causal == 1 && n0 > m0 + (BM - 1)) return;
  const int z = blockIdx.z;
  const short* Ab = p.A + (size_t)z * p.a_bs;
  const short* Bb = p.B + (size_t)z * p.b_bs;
  int kbeg = 0, kend = p.K;
  if (p.kchunk) { kbeg = z * p.kchunk; kend = kbeg + p.kchunk; }
  if (p.causal == 2) { int lim = m0 + BM; if (lim < kend) kend = lim; }

  __shared__ __align__(16) short As[BM * BK];   // swizzled: chunk c of row r at pos (c + (r>>1)) & 3
  __shared__ __align__(16) short Bs[BN * BK];

  const int tid = threadIdx.x;
  const int lane = tid & 63, wave = tid >> 6;
  const int wm = (wave >> 1) * 64, wn = (wave & 1) * 64;
  const int l15 = lane & 15, quad = lane >> 4;
  const int rl = lane >> 2, pl = lane & 3;

  floatx4 acc[4][4];
#pragma unroll
  for (int i = 0; i < 4; i++)
#pragma unroll
    for (int j = 0; j < 4; j++) acc[i][j] = (floatx4){0.f, 0.f, 0.f, 0.f};

  for (int k0 = kbeg; k0 < kend; k0 += BK) {
    const short* Ak = Ab; int kb = k0;
    if (p.a_kh) { int h = k0 / p.a_kh; Ak = Ab + (size_t)h * p.a_hs; kb = k0 - h * p.a_kh; }
#pragma unroll
    for (int s = 0; s < 2; s++) {
      const int win = wave * 2 + s;            // 8 windows of 16 rows (1 KB each)
      const int row = win * 16 + rl;
      const int cs = (pl - (row >> 1)) & 3;    // global chunk landing at LDS pos pl
      const short* ga = Ak + (size_t)(m0 + row) * p.lda + kb + cs * 8;
      const short* gb = Bb + (size_t)(n0 + row) * p.ldb + k0 + cs * 8;
#ifdef HAS_GLLD
      lds_dma16(ga, &As[win * 512]);
      lds_dma16(gb, &Bs[win * 512]);
#else
      *(int4*)&As[win * 512 + lane * 8] = *(const int4*)ga;
      *(int4*)&Bs[win * 512 + lane * 8] = *(const int4*)gb;
#endif
    }
    __syncthreads();
    bf16x8 fa[4], fb[4];
#pragma unroll
    for (int i = 0; i < 4; i++) {
      const int ra = wm + i * 16 + l15;
      fa[i] = *(const bf16x8*)&As[ra * 32 + ((quad + (ra >> 1)) & 3) * 8];
      const int rb = wn + i * 16 + l15;
      fb[i] = *(const bf16x8*)&Bs[rb * 32 + ((quad + (rb >> 1)) & 3) * 8];
    }
#pragma unroll
    for (int i = 0; i < 4; i++)
#pragma unroll
      for (int j = 0; j < 4; j++)
        acc[i][j] = __builtin_amdgcn_mfma_f32_16x16x32_bf16(fa[i], fb[j], acc[i][j], 0, 0, 0);
    __syncthreads();
  }

  // C/D layout (m89): col = lane&15, row = quad*4 + reg
  const long coff = (long)(z % p.zmod) * p.cz0 + (long)(z / p.zmod) * p.cz1;
#pragma unroll
  for (int j = 0; j < 4; j++) {
    const int col = n0 + wn + j * 16 + l15;
    if constexpr (MODE == 0) {
#pragma unroll
      for (int i = 0; i < 4; i++) {
        const int rb = m0 + wm + i * 16 + quad * 4;
#pragma unroll
        for (int r = 0; r < 4; r++)
          p.C0[coff + (size_t)(rb + r) * p.ldc + col] = f2b(acc[i][j][r] * p.alpha);
      }
    } else if constexpr (MODE == 5) {
      const int part = (n0 + wn) / 768;        // wave-uniform: 0=q, 1=k, 2=v
      const int cc = col - part * 768;
      const float* bp_ = (part == 0) ? p.bias0 : ((part == 1) ? p.bias1 : p.bias2);
      const float bvv = bp_[(p.zoff + z) * 768 + cc];
      if (part < 2) {
        short* dst = part ? p.C1 : p.C0;
#pragma unroll
        for (int i = 0; i < 4; i++) {
          const int rb = m0 + wm + i * 16 + quad * 4;
#pragma unroll
          for (int r = 0; r < 4; r++)
            dst[(size_t)z * p.c_zs + (size_t)(rb + r) * 768 + cc] = f2b(acc[i][j][r] + bvv);
        }
      } else {
#pragma unroll
        for (int i = 0; i < 4; i++) {
          const int rb = m0 + wm + i * 16 + quad * 4;
          short4 pk;
          pk.x = f2b(acc[i][j][0] + bvv);
          pk.y = f2b(acc[i][j][1] + bvv);
          pk.z = f2b(acc[i][j][2] + bvv);
          pk.w = f2b(acc[i][j][3] + bvv);
          const size_t addr = (((size_t)z * 4 + (rb >> 10)) * 768 + cc) * 1024 + (rb & 1023);
          *(short4*)&p.C2[addr] = pk;
        }
      }
    } else if constexpr (MODE == 4) {
#pragma unroll
      for (int i = 0; i < 4; i++) {
        const int rb = m0 + wm + i * 16 + quad * 4;
#pragma unroll
        for (int r = 0; r < 4; r++)
          p.Cf[(size_t)z * p.c_zs + (size_t)(rb + r) * p.ldc + col] = acc[i][j][r];
      }
    } else {  // MODE 3: exact gelu
      const float bvv = p.bias0[col];
#pragma unroll
      for (int i = 0; i < 4; i++) {
        const int rb = m0 + wm + i * 16 + quad * 4;
#pragma unroll
        for (int r = 0; r < 4; r++) {
          float t = acc[i][j][r] + bvv;
          p.C0[(size_t)(rb + r) * p.ldc + col] = f2b(0.5f * t * (1.0f + erff(t * 0.70710678118654752440f)));
        }
      }
    }
  }
}

__global__ void __launch_bounds__(256) ln_kernel(
    const float* __restrict__ in, const float* __restrict__ g, const float* __restrict__ b,
    float* __restrict__ outf, short* __restrict__ outb)
{
  const long r = blockIdx.x;
  const float* x = in + r * 768;
  const int tid = threadIdx.x;
  float v0 = x[tid], v1 = x[tid + 256], v2 = x[tid + 512];
  float s = v0 + v1 + v2;
  float sq = v0 * v0 + v1 * v1 + v2 * v2;
  __shared__ float red[8];
  int lane = tid & 63, wave = tid >> 6;
#pragma unroll
  for (int o = 1; o < 64; o <<= 1) { s += __shfl_xor(s, o); sq += __shfl_xor(sq, o); }
  if (lane == 0) { red[wave] = s; red[4 + wave] = sq; }
  __syncthreads();
  s = red[0] + red[1] + red[2] + red[3];
  sq = red[4] + red[5] + red[6] + red[7];
  float mean = s * (1.0f / 768.0f);
  float var = sq * (1.0f / 768.0f) - mean * mean;
  float inv = rsqrtf(var + 1e-5f);
#pragma unroll
  for (int u = 0; u < 3; u++) {
    int c = tid + u * 256;
    float v = (u == 0) ? v0 : ((u == 1) ? v1 : v2);
    float y = (v - mean) * inv * g[c] + b[c];
    outf[r * 768 + c] = y;
    outb[r * 768 + c] = f2b(y);
  }
}

// y = sum(partials) + bias + resid; then LayerNorm(y)*g+b -> outf (fp32) + outb (bf16).
__global__ void __launch_bounds__(256) reduce_ln_kernel(
    const float* __restrict__ part, long pzs, int nsplit,
    const float* __restrict__ bias, const float* __restrict__ resid,
    const float* __restrict__ g, const float* __restrict__ b,
    float* __restrict__ outf, short* __restrict__ outb)
{
  const long r = blockIdx.x;
  const int tid = threadIdx.x;
  float y[3];
#pragma unroll
  for (int u = 0; u < 3; u++) {
    const int c = tid + u * 256;
    const size_t idx = (size_t)r * 768 + c;
    float s = part[idx];
    for (int zz = 1; zz < nsplit; zz++) s += part[(size_t)zz * pzs + idx];
    y[u] = s + bias[c] + resid[idx];
  }
  float s = y[0] + y[1] + y[2];
  float sq = y[0] * y[0] + y[1] * y[1] + y[2] * y[2];
  __shared__ float red[8];
  int lane = tid & 63, wave = tid >> 6;
#pragma unroll
  for (int o = 1; o < 64; o <<= 1) { s += __shfl_xor(s, o); sq += __shfl_xor(sq, o); }
  if (lane == 0) { red[wave] = s; red[4 + wave] = sq; }
  __syncthreads();
  s = red[0] + red[1] + red[2] + red[3];
  sq = red[4] + red[5] + red[6] + red[7];
  float mean = s * (1.0f / 768.0f);
  float var = sq * (1.0f / 768.0f) - mean * mean;
  float inv = rsqrtf(var + 1e-5f);
#pragma unroll
  for (int u = 0; u < 3; u++) {
    const int c = tid + u * 256;
    const float v = (y[u] - mean) * inv * g[c] + b[c];
    outf[(size_t)r * 768 + c] = v;
    outb[(size_t)r * 768 + c] = f2b(v);
  }
}

__global__ void __launch_bounds__(256) softmax_kernel(short* __restrict__ sc)
{
  const long gr = blockIdx.x;
  const int i = (int)(gr & 1023);
  short* row = sc + (gr >> 10) * (1024L * 1024) + (long)i * 1024;
  const int L = i + 1;
  const int tid = threadIdx.x;
  const int lane = tid & 63, wave = tid >> 6;
  __shared__ float red[4];
  float v[4];
  float mx = -3.0e38f;
#pragma unroll
  for (int s = 0; s < 4; s++) {
    int j = tid + s * 256;
    v[s] = (j < L) ? b2f(row[j]) : -3.0e38f;
    mx = fmaxf(mx, v[s]);
  }
#pragma unroll
  for (int o = 1; o < 64; o <<= 1) mx = fmaxf(mx, __shfl_xor(mx, o));
  if (lane == 0) red[wave] = mx;
  __syncthreads();
  mx = fmaxf(fmaxf(red[0], red[1]), fmaxf(red[2], red[3]));
  __syncthreads();
  float sum = 0.0f;
#pragma unroll
  for (int s = 0; s < 4; s++) {
    int j = tid + s * 256;
    if (j < L) { v[s] = __expf(v[s] - mx); sum += v[s]; }
  }
#pragma unroll
  for (int o = 1; o < 64; o <<= 1) sum += __shfl_xor(sum, o);
  if (lane == 0) red[wave] = sum;
  __syncthreads();
  sum = red[0] + red[1] + red[2] + red[3];
  float inv = 1.0f / sum;
#pragma unroll
  for (int s = 0; s < 4; s++) {
    int j = tid + s * 256;
    if (j < L) row[j] = f2b(v[s] * inv);
  }
  const int hi = i | 127;
  for (int j = L + tid; j <= hi; j += 256) row[j] = 0;
}

__global__ void __launch_bounds__(256) reduce_kernel(
    const float* __restrict__ part, long pzs, int nsplit,
    const float* __restrict__ bias, const float* __restrict__ resid,
    float* __restrict__ out)
{
  const size_t idx = ((size_t)blockIdx.x * 256 + threadIdx.x) * 4;
  float4 s = *(const float4*)&part[idx];
  for (int zz = 1; zz < nsplit; zz++) {
    float4 q = *(const float4*)&part[(size_t)zz * pzs + idx];
    s.x += q.x; s.y += q.y; s.z += q.z; s.w += q.w;
  }
  const int c = (int)(idx % 768);
  float4 b = *(const float4*)&bias[c];
  float4 r = *(const float4*)&resid[idx];
  *(float4*)&out[idx] = make_float4(s.x + b.x + r.x, s.y + b.y + r.y,
                                    s.z + b.z + r.z, s.w + b.w + r.w);
}

// W[R][C] fp32 -> Wt[C][R] bf16, per-z src/dst strides
__global__ void __launch_bounds__(256) transpose_kernel(
    const float* __restrict__ W, short* __restrict__ Wt, int R, int C, long szs, long dzs)
{
  __shared__ float tile[32][33];
  const int c0 = blockIdx.x * 32, r0 = blockIdx.y * 32;
  const float* Wz = W + (size_t)blockIdx.z * szs;
  short* Wtz = Wt + (size_t)blockIdx.z * dzs;
  const int tx = threadIdx.x, ty = threadIdx.y;
#pragma unroll
  for (int i = 0; i < 32; i += 8)
    tile[ty + i][tx] = Wz[(size_t)(r0 + ty + i) * C + (c0 + tx)];
  __syncthreads();
#pragma unroll
  for (int i = 0; i < 32; i += 8)
    Wtz[(size_t)(c0 + ty + i) * R + (r0 + tx)] = f2b(tile[tx][ty + i]);
}

extern "C" void kernel_launch(void* const* d_in, const int* in_sizes, int n_in,
                              void* d_out, int out_size, void* d_ws, size_t ws_size,
                              hipStream_t stream)
{
  (void)in_sizes; (void)n_in; (void)out_size;
  const float* inputs = (const float*)d_in[0];
  const float* g1  = (const float*)d_in[1];
  const float* b1  = (const float*)d_in[2];
  const float* Wq  = (const float*)d_in[3];
  const float* bq  = (const float*)d_in[4];
  const float* Wk  = (const float*)d_in[5];
  const float* bk  = (const float*)d_in[6];
  const float* Wv  = (const float*)d_in[7];
  const float* bv  = (const float*)d_in[8];
  const float* Wc  = (const float*)d_in[9];
  const float* bc  = (const float*)d_in[10];
  const float* g2  = (const float*)d_in[11];
  const float* b2  = (const float*)d_in[12];
  const float* Wfc = (const float*)d_in[13];
  const float* bfc = (const float*)d_in[14];
  const float* Wp  = (const float*)d_in[15];
  const float* bp  = (const float*)d_in[16];
  float* out = (float*)d_out;

  const size_t NS = 4096, E = 768, S = 1024;

  char* base = (char*)d_ws;
  size_t off = 0;
  auto alloc = [&](size_t n) { char* r = base + off; off = (off + n + 255) & ~(size_t)255; return r; };

  // ---- persistent region (live across whole launch) ----
  float* x_f  = (float*)alloc(NS * E * 4);
  short* x_b  = (short*)alloc(NS * E * 2);
  short* Wqkv = (short*)alloc(12 * 3 * E * E * 2);   // [h][{q,k,v}][768][768] bf16 (B^T)
  short* WcT  = (short*)alloc(E * 9216 * 2);
  short* WfcT = (short*)alloc(3072 * E * 2);
  short* WpT  = (short*)alloc(E * 3072 * 2);
  short* cat  = (short*)alloc(12 * NS * E * 2);      // head-major [h][4096][768]; aliases partB later

  // ---- overlay region R: attention pool, then post-attention buffers ----
  char* Rp = base + off;
  const size_t R_size = (ws_size > off) ? (ws_size - off) : 0;

  const size_t per_h = 3 * (NS * E * 2) + 4 * S * S * 2;
  static const int Gs[5] = {6, 4, 3, 2, 1};
  int G = 1;
  for (int i = 0; i < 5; i++)
    if ((size_t)Gs[i] * per_h <= R_size) { G = Gs[i]; break; }

  short* q_g  = (short*)Rp;
  short* k_g  = q_g + (size_t)G * NS * E;
  short* vT_g = k_g + (size_t)G * NS * E;            // [z*4+n][768][1024]
  short* sc_g = vT_g + (size_t)G * NS * E;           // [z*4+n][1024][1024]

  // post-attention overlay (attention pool dead by then)
  size_t o2 = 0;
  float* partA = (float*)(Rp + o2); o2 += 4 * NS * E * 4;   // c_proj split-K=4 partials
  float* y2_f  = (float*)(Rp + o2); o2 += NS * E * 4;
  short* y2_b  = (short*)(Rp + o2); o2 += NS * E * 2;
  short* h_b   = (short*)(Rp + o2); o2 += NS * 3072 * 2;
  float* partB = (float*)cat;                               // 50.3 MB <= cat (75.5 MB)

  const dim3 tb(32, 8);
  transpose_kernel<<<dim3(24, 24, 12), tb, 0, stream>>>(Wq, Wqkv,         768, 768, (long)(E*E), (long)(3*E*E));
  transpose_kernel<<<dim3(24, 24, 12), tb, 0, stream>>>(Wk, Wqkv + E*E,   768, 768, (long)(E*E), (long)(3*E*E));
  transpose_kernel<<<dim3(24, 24, 12), tb, 0, stream>>>(Wv, Wqkv + 2*E*E, 768, 768, (long)(E*E), (long)(3*E*E));
  transpose_kernel<<<dim3(24, 288, 1), tb, 0, stream>>>(Wc, WcT, 9216, 768, 0, 0);
  transpose_kernel<<<dim3(96, 24, 1),  tb, 0, stream>>>(Wfc, WfcT, 768, 3072, 0, 0);
  transpose_kernel<<<dim3(24, 96, 1),  tb, 0, stream>>>(Wp, WpT, 3072, 768, 0, 0);

  ln_kernel<<<4096, 256, 0, stream>>>(inputs, g1, b1, x_f, x_b);

  const float sca = 0.03608439182435161f;  // 1/sqrt(768)
  for (int h0 = 0; h0 < 12; h0 += G) {
    {  // merged QKV: N = 2304 per head; grid.x = m (32, XCD-aligned)
      GP p{};
      p.A = x_b; p.lda = 768; p.a_bs = 0;
      p.B = Wqkv + (size_t)h0 * 3 * E * E; p.ldb = 768; p.b_bs = (long)(3 * E * E);
      p.bias0 = bq; p.bias1 = bk; p.bias2 = bv; p.zoff = h0;
      p.C0 = q_g; p.C1 = k_g; p.C2 = vT_g; p.c_zs = (long)(NS * E);
      p.ldc = 768; p.zmod = 1;
      p.K = 768; p.alpha = 1.0f;
      gemm_kernel<5><<<dim3(32, 18, G), 256, 0, stream>>>(p);
    }
    {  // scores = q k^T / sqrt(E)
      GP p{};
      p.A = q_g; p.lda = 768; p.a_bs = (long)(S * E);
      p.B = k_g; p.ldb = 768; p.b_bs = (long)(S * E);
      p.C0 = sc_g; p.ldc = 1024; p.zmod = 1; p.cz0 = 0; p.cz1 = (long)(S * S);
      p.K = 768; p.alpha = sca; p.causal = 1;
      gemm_kernel<0><<<dim3(8, 8, 4 * G), 256, 0, stream>>>(p);
    }
    softmax_kernel<<<4 * G * 1024, 256, 0, stream>>>(sc_g);
    {  // heads = attn @ v -> cat[h][4096][768]
      GP p{};
      p.A = sc_g; p.lda = 1024; p.a_bs = (long)(S * S);
      p.B = vT_g; p.ldb = 1024; p.b_bs = (long)(E * S);
      p.C0 = cat + (size_t)h0 * NS * E; p.ldc = 768;
      p.zmod = 4; p.cz0 = (long)(S * E); p.cz1 = (long)(NS * E);
      p.K = 1024; p.alpha = 1.0f; p.causal = 2;
      gemm_kernel<0><<<dim3(8, 6, 4 * G), 256, 0, stream>>>(p);
    }
  }

  {  // c_proj split-K=4 (kchunk = 2304 = 3 heads) over head-major cat
    GP p{};
    p.A = cat; p.lda = 768; p.a_kh = 768; p.a_hs = (long)(NS * E);
    p.B = WcT; p.ldb = 9216;
    p.Cf = partA; p.ldc = 768; p.c_zs = (long)(NS * E); p.zmod = 1;
    p.K = 9216; p.kchunk = 2304; p.alpha = 1.0f;
    gemm_kernel<4><<<dim3(32, 6, 4), 256, 0, stream>>>(p);
  }
  // y = sum(partA) + bc + x_f; y2 = LN(y)  (fused; y never materialized)
  reduce_ln_kernel<<<4096, 256, 0, stream>>>(partA, (long)(NS * E), 4, bc, x_f,
                                             g2, b2, y2_f, y2_b);

  {  // fc + exact gelu
    GP p{};
    p.A = y2_b; p.lda = 768;
    p.B = WfcT; p.ldb = 768;
    p.bias0 = bfc; p.C0 = h_b; p.ldc = 3072; p.zmod = 1;
    p.K = 768; p.alpha = 1.0f;
    gemm_kernel<3><<<dim3(32, 24, 1), 256, 0, stream>>>(p);
  }
  {  // proj split-K=4
    GP p{};
    p.A = h_b; p.lda = 3072;
    p.B = WpT; p.ldb = 3072;
    p.Cf = partB; p.ldc = 768; p.c_zs = (long)(NS * E); p.zmod = 1;
    p.K = 3072; p.kchunk = 768; p.alpha = 1.0f;
    gemm_kernel<4><<<dim3(32, 6, 4), 256, 0, stream>>>(p);
  }
  reduce_kernel<<<3072, 256, 0, stream>>>(partB, (long)(NS * E), 4, bp, y2_f, out);
}

// Round 4
// 971.663 us; speedup vs baseline: 2.2593x; 1.0385x over previous
//
#include <hip/hip_runtime.h>
#include <hip/hip_bf16.h>
#include <math.h>

// Transformer block on gfx950. bf16 MFMA GEMMs (16x16x32), fp32 accumulate.
// Round-4: BK=64 (32 MFMA per barrier, AITER ratio), per-row LDS chunk rotation
// (2-way-only bank access per quarter-wave), distinct kernel names for rocprof
// attribution, reversed m-order for the causal PV GEMM (long blocks first).

#define BM 128
#define BN 128
#define BK 64

typedef __attribute__((ext_vector_type(8))) short bf16x8;
typedef __attribute__((ext_vector_type(4))) float floatx4;

__device__ __forceinline__ short f2b(float f) {
  __hip_bfloat16 h = __float2bfloat16(f);
  return *reinterpret_cast<short*>(&h);
}
__device__ __forceinline__ float b2f(short s) {
  unsigned u = ((unsigned)(unsigned short)s) << 16;
  return __uint_as_float(u);
}

#if defined(__has_builtin)
#if __has_builtin(__builtin_amdgcn_global_load_lds)
#define HAS_GLLD 1
#endif
#endif

#ifdef HAS_GLLD
__device__ __forceinline__ void lds_dma16(const short* g, short* l) {
  __builtin_amdgcn_global_load_lds(
      (const __attribute__((address_space(1))) void*)g,
      (__attribute__((address_space(3))) void*)l, 16, 0, 0);
}
#endif

struct GP {
  const short* A; const short* B;
  long a_bs, b_bs;
  int lda, ldb;
  int a_kh; long a_hs;          // if a_kh>0: A addr = (k/a_kh)*a_hs + row*lda + k%a_kh
  const float* bias0; const float* bias1; const float* bias2;
  short* C0; short* C1; short* C2;
  float* Cf;
  int ldc, zmod;
  long cz0, cz1, c_zs;
  int K, kchunk;                // kchunk>0: this z handles K range [z*kchunk, +kchunk)
  float alpha;
  int zoff;
};

// MODE 0: C0 = bf16(acc*alpha)            (CAUSAL=1 tile-skip; CAUSAL=2 K-limit)
// MODE 3: C0 = bf16(gelu(acc + bias0[col]))
// MODE 4: Cf[z*c_zs + ...] = acc          (split-K fp32 partial)
// MODE 5: QKV routing by column part: q->C0, k->C1, v->C2 (transposed layout)
template<int MODE, int CAUSAL>
__device__ __forceinline__ void gemm_body(const GP& p)
{
  int bx = blockIdx.x;
  if (CAUSAL == 2) bx = gridDim.x - 1 - bx;   // longest K first
  const int m0 = bx * BM, n0 = blockIdx.y * BN;
  if (CAUSAL == 1 && n0 > m0 + (BM - 1)) return;
  const int z = blockIdx.z;
  const short* Ab = p.A + (size_t)z * p.a_bs;
  const short* Bb = p.B + (size_t)z * p.b_bs;
  int kbeg = 0, kend = p.K;
  if (p.kchunk) { kbeg = z * p.kchunk; kend = kbeg + p.kchunk; }
  if (CAUSAL == 2) { int lim = m0 + BM; if (lim < kend) kend = lim; }

  // Row = 128 B (8 chunks of 16 B); chunk c of row r stored at pos (c + r) & 7.
  // ds_read_b128: within a 16-lane quarter (fixed quad) rows cover each rotation
  // twice -> 2-way bank aliasing only (free, m136).
  __shared__ __align__(16) short As[BM * BK];
  __shared__ __align__(16) short Bs[BN * BK];

  const int tid = threadIdx.x;
  const int lane = tid & 63, wave = tid >> 6;
  const int wm = (wave >> 1) * 64, wn = (wave & 1) * 64;
  const int l15 = lane & 15, quad = lane >> 4;
  const int rl = lane >> 3, pl = lane & 7;    // 8 rows x 8 chunk-slots per window

  floatx4 acc[4][4];
#pragma unroll
  for (int i = 0; i < 4; i++)
#pragma unroll
    for (int j = 0; j < 4; j++) acc[i][j] = (floatx4){0.f, 0.f, 0.f, 0.f};

  const int cs = (pl - rl) & 7;               // global chunk landing at LDS pos pl

  for (int k0 = kbeg; k0 < kend; k0 += BK) {
    const short* Ak = Ab; int kb = k0;
    if (p.a_kh) { int h = k0 / p.a_kh; Ak = Ab + (size_t)h * p.a_hs; kb = k0 - h * p.a_kh; }
#pragma unroll
    for (int s = 0; s < 4; s++) {
      const int win = wave * 4 + s;           // 16 windows of 8 rows (1 KB each)
      const int row = win * 8 + rl;
      const short* ga = Ak + (size_t)(m0 + row) * p.lda + kb + cs * 8;
      const short* gb = Bb + (size_t)(n0 + row) * p.ldb + k0 + cs * 8;
#ifdef HAS_GLLD
      lds_dma16(ga, &As[win * 512]);
      lds_dma16(gb, &Bs[win * 512]);
#else
      *(int4*)&As[win * 512 + lane * 8] = *(const int4*)ga;
      *(int4*)&Bs[win * 512 + lane * 8] = *(const int4*)gb;
#endif
    }
    __syncthreads();
#pragma unroll
    for (int t = 0; t < 2; t++) {             // two 16x16x32 k-steps per BK=64 tile
      bf16x8 fa[4], fb[4];
#pragma unroll
      for (int i = 0; i < 4; i++) {
        const int ra = wm + i * 16 + l15;
        fa[i] = *(const bf16x8*)&As[ra * 64 + (((t << 2) + quad + ra) & 7) * 8];
        const int rb = wn + i * 16 + l15;
        fb[i] = *(const bf16x8*)&Bs[rb * 64 + (((t << 2) + quad + rb) & 7) * 8];
      }
#pragma unroll
      for (int i = 0; i < 4; i++)
#pragma unroll
        for (int j = 0; j < 4; j++)
          acc[i][j] = __builtin_amdgcn_mfma_f32_16x16x32_bf16(fa[i], fb[j], acc[i][j], 0, 0, 0);
    }
    __syncthreads();
  }

  // C/D layout (m89): col = lane&15, row = quad*4 + reg
  const long coff = (long)(z % p.zmod) * p.cz0 + (long)(z / p.zmod) * p.cz1;
#pragma unroll
  for (int j = 0; j < 4; j++) {
    const int col = n0 + wn + j * 16 + l15;
    if constexpr (MODE == 0) {
#pragma unroll
      for (int i = 0; i < 4; i++) {
        const int rb = m0 + wm + i * 16 + quad * 4;
#pragma unroll
        for (int r = 0; r < 4; r++)
          p.C0[coff + (size_t)(rb + r) * p.ldc + col] = f2b(acc[i][j][r] * p.alpha);
      }
    } else if constexpr (MODE == 5) {
      const int part = (n0 + wn) / 768;        // wave-uniform: 0=q, 1=k, 2=v
      const int cc = col - part * 768;
      const float* bp_ = (part == 0) ? p.bias0 : ((part == 1) ? p.bias1 : p.bias2);
      const float bvv = bp_[(p.zoff + z) * 768 + cc];
      if (part < 2) {
        short* dst = part ? p.C1 : p.C0;
#pragma unroll
        for (int i = 0; i < 4; i++) {
          const int rb = m0 + wm + i * 16 + quad * 4;
#pragma unroll
          for (int r = 0; r < 4; r++)
            dst[(size_t)z * p.c_zs + (size_t)(rb + r) * 768 + cc] = f2b(acc[i][j][r] + bvv);
        }
      } else {
#pragma unroll
        for (int i = 0; i < 4; i++) {
          const int rb = m0 + wm + i * 16 + quad * 4;
          short4 pk;
          pk.x = f2b(acc[i][j][0] + bvv);
          pk.y = f2b(acc[i][j][1] + bvv);
          pk.z = f2b(acc[i][j][2] + bvv);
          pk.w = f2b(acc[i][j][3] + bvv);
          const size_t addr = (((size_t)z * 4 + (rb >> 10)) * 768 + cc) * 1024 + (rb & 1023);
          *(short4*)&p.C2[addr] = pk;
        }
      }
    } else if constexpr (MODE == 4) {
#pragma unroll
      for (int i = 0; i < 4; i++) {
        const int rb = m0 + wm + i * 16 + quad * 4;
#pragma unroll
        for (int r = 0; r < 4; r++)
          p.Cf[(size_t)z * p.c_zs + (size_t)(rb + r) * p.ldc + col] = acc[i][j][r];
      }
    } else {  // MODE 3: exact gelu
      const float bvv = p.bias0[col];
#pragma unroll
      for (int i = 0; i < 4; i++) {
        const int rb = m0 + wm + i * 16 + quad * 4;
#pragma unroll
        for (int r = 0; r < 4; r++) {
          float t = acc[i][j][r] + bvv;
          p.C0[(size_t)(rb + r) * p.ldc + col] = f2b(0.5f * t * (1.0f + erff(t * 0.70710678118654752440f)));
        }
      }
    }
  }
}

__global__ void __launch_bounds__(256) gemm_qkv(GP p)   { gemm_body<5, 0>(p); }
__global__ void __launch_bounds__(256) gemm_sco(GP p)   { gemm_body<0, 1>(p); }
__global__ void __launch_bounds__(256) gemm_pv(GP p)    { gemm_body<0, 2>(p); }
__global__ void __launch_bounds__(256) gemm_cproj(GP p) { gemm_body<4, 0>(p); }
__global__ void __launch_bounds__(256) gemm_fc(GP p)    { gemm_body<3, 0>(p); }
__global__ void __launch_bounds__(256) gemm_mproj(GP p) { gemm_body<4, 0>(p); }

__global__ void __launch_bounds__(256) ln_kernel(
    const float* __restrict__ in, const float* __restrict__ g, const float* __restrict__ b,
    float* __restrict__ outf, short* __restrict__ outb)
{
  const long r = blockIdx.x;
  const float* x = in + r * 768;
  const int tid = threadIdx.x;
  float v0 = x[tid], v1 = x[tid + 256], v2 = x[tid + 512];
  float s = v0 + v1 + v2;
  float sq = v0 * v0 + v1 * v1 + v2 * v2;
  __shared__ float red[8];
  int lane = tid & 63, wave = tid >> 6;
#pragma unroll
  for (int o = 1; o < 64; o <<= 1) { s += __shfl_xor(s, o); sq += __shfl_xor(sq, o); }
  if (lane == 0) { red[wave] = s; red[4 + wave] = sq; }
  __syncthreads();
  s = red[0] + red[1] + red[2] + red[3];
  sq = red[4] + red[5] + red[6] + red[7];
  float mean = s * (1.0f / 768.0f);
  float var = sq * (1.0f / 768.0f) - mean * mean;
  float inv = rsqrtf(var + 1e-5f);
#pragma unroll
  for (int u = 0; u < 3; u++) {
    int c = tid + u * 256;
    float v = (u == 0) ? v0 : ((u == 1) ? v1 : v2);
    float y = (v - mean) * inv * g[c] + b[c];
    outf[r * 768 + c] = y;
    outb[r * 768 + c] = f2b(y);
  }
}

// y = sum(partials) + bias + resid; then LayerNorm(y)*g+b -> outf (fp32) + outb (bf16).
__global__ void __launch_bounds__(256) reduce_ln_kernel(
    const float* __restrict__ part, long pzs, int nsplit,
    const float* __restrict__ bias, const float* __restrict__ resid,
    const float* __restrict__ g, const float* __restrict__ b,
    float* __restrict__ outf, short* __restrict__ outb)
{
  const long r = blockIdx.x;
  const int tid = threadIdx.x;
  float y[3];
#pragma unroll
  for (int u = 0; u < 3; u++) {
    const int c = tid + u * 256;
    const size_t idx = (size_t)r * 768 + c;
    float s = part[idx];
    for (int zz = 1; zz < nsplit; zz++) s += part[(size_t)zz * pzs + idx];
    y[u] = s + bias[c] + resid[idx];
  }
  float s = y[0] + y[1] + y[2];
  float sq = y[0] * y[0] + y[1] * y[1] + y[2] * y[2];
  __shared__ float red[8];
  int lane = tid & 63, wave = tid >> 6;
#pragma unroll
  for (int o = 1; o < 64; o <<= 1) { s += __shfl_xor(s, o); sq += __shfl_xor(sq, o); }
  if (lane == 0) { red[wave] = s; red[4 + wave] = sq; }
  __syncthreads();
  s = red[0] + red[1] + red[2] + red[3];
  sq = red[4] + red[5] + red[6] + red[7];
  float mean = s * (1.0f / 768.0f);
  float var = sq * (1.0f / 768.0f) - mean * mean;
  float inv = rsqrtf(var + 1e-5f);
#pragma unroll
  for (int u = 0; u < 3; u++) {
    const int c = tid + u * 256;
    const float v = (y[u] - mean) * inv * g[c] + b[c];
    outf[(size_t)r * 768 + c] = v;
    outb[(size_t)r * 768 + c] = f2b(v);
  }
}

__global__ void __launch_bounds__(256) softmax_kernel(short* __restrict__ sc)
{
  const long gr = blockIdx.x;
  const int i = (int)(gr & 1023);
  short* row = sc + (gr >> 10) * (1024L * 1024) + (long)i * 1024;
  const int L = i + 1;
  const int tid = threadIdx.x;
  const int lane = tid & 63, wave = tid >> 6;
  __shared__ float red[4];
  float v[4];
  float mx = -3.0e38f;
#pragma unroll
  for (int s = 0; s < 4; s++) {
    int j = tid + s * 256;
    v[s] = (j < L) ? b2f(row[j]) : -3.0e38f;
    mx = fmaxf(mx, v[s]);
  }
#pragma unroll
  for (int o = 1; o < 64; o <<= 1) mx = fmaxf(mx, __shfl_xor(mx, o));
  if (lane == 0) red[wave] = mx;
  __syncthreads();
  mx = fmaxf(fmaxf(red[0], red[1]), fmaxf(red[2], red[3]));
  __syncthreads();
  float sum = 0.0f;
#pragma unroll
  for (int s = 0; s < 4; s++) {
    int j = tid + s * 256;
    if (j < L) { v[s] = __expf(v[s] - mx); sum += v[s]; }
  }
#pragma unroll
  for (int o = 1; o < 64; o <<= 1) sum += __shfl_xor(sum, o);
  if (lane == 0) red[wave] = sum;
  __syncthreads();
  sum = red[0] + red[1] + red[2] + red[3];
  float inv = 1.0f / sum;
#pragma unroll
  for (int s = 0; s < 4; s++) {
    int j = tid + s * 256;
    if (j < L) row[j] = f2b(v[s] * inv);
  }
  const int hi = i | 127;
  for (int j = L + tid; j <= hi; j += 256) row[j] = 0;
}

__global__ void __launch_bounds__(256) reduce_kernel(
    const float* __restrict__ part, long pzs, int nsplit,
    const float* __restrict__ bias, const float* __restrict__ resid,
    float* __restrict__ out)
{
  const size_t idx = ((size_t)blockIdx.x * 256 + threadIdx.x) * 4;
  float4 s = *(const float4*)&part[idx];
  for (int zz = 1; zz < nsplit; zz++) {
    float4 q = *(const float4*)&part[(size_t)zz * pzs + idx];
    s.x += q.x; s.y += q.y; s.z += q.z; s.w += q.w;
  }
  const int c = (int)(idx % 768);
  float4 b = *(const float4*)&bias[c];
  float4 r = *(const float4*)&resid[idx];
  *(float4*)&out[idx] = make_float4(s.x + b.x + r.x, s.y + b.y + r.y,
                                    s.z + b.z + r.z, s.w + b.w + r.w);
}

// W[R][C] fp32 -> Wt[C][R] bf16, per-z src/dst strides
__global__ void __launch_bounds__(256) transpose_kernel(
    const float* __restrict__ W, short* __restrict__ Wt, int R, int C, long szs, long dzs)
{
  __shared__ float tile[32][33];
  const int c0 = blockIdx.x * 32, r0 = blockIdx.y * 32;
  const float* Wz = W + (size_t)blockIdx.z * szs;
  short* Wtz = Wt + (size_t)blockIdx.z * dzs;
  const int tx = threadIdx.x, ty = threadIdx.y;
#pragma unroll
  for (int i = 0; i < 32; i += 8)
    tile[ty + i][tx] = Wz[(size_t)(r0 + ty + i) * C + (c0 + tx)];
  __syncthreads();
#pragma unroll
  for (int i = 0; i < 32; i += 8)
    Wtz[(size_t)(c0 + ty + i) * R + (r0 + tx)] = f2b(tile[tx][ty + i]);
}

extern "C" void kernel_launch(void* const* d_in, const int* in_sizes, int n_in,
                              void* d_out, int out_size, void* d_ws, size_t ws_size,
                              hipStream_t stream)
{
  (void)in_sizes; (void)n_in; (void)out_size;
  const float* inputs = (const float*)d_in[0];
  const float* g1  = (const float*)d_in[1];
  const float* b1  = (const float*)d_in[2];
  const float* Wq  = (const float*)d_in[3];
  const float* bq  = (const float*)d_in[4];
  const float* Wk  = (const float*)d_in[5];
  const float* bk  = (const float*)d_in[6];
  const float* Wv  = (const float*)d_in[7];
  const float* bv  = (const float*)d_in[8];
  const float* Wc  = (const float*)d_in[9];
  const float* bc  = (const float*)d_in[10];
  const float* g2  = (const float*)d_in[11];
  const float* b2  = (const float*)d_in[12];
  const float* Wfc = (const float*)d_in[13];
  const float* bfc = (const float*)d_in[14];
  const float* Wp  = (const float*)d_in[15];
  const float* bp  = (const float*)d_in[16];
  float* out = (float*)d_out;

  const size_t NS = 4096, E = 768, S = 1024;

  char* base = (char*)d_ws;
  size_t off = 0;
  auto alloc = [&](size_t n) { char* r = base + off; off = (off + n + 255) & ~(size_t)255; return r; };

  // ---- persistent region (live across whole launch) ----
  float* x_f  = (float*)alloc(NS * E * 4);
  short* x_b  = (short*)alloc(NS * E * 2);
  short* Wqkv = (short*)alloc(12 * 3 * E * E * 2);   // [h][{q,k,v}][768][768] bf16 (B^T)
  short* WcT  = (short*)alloc(E * 9216 * 2);
  short* WfcT = (short*)alloc(3072 * E * 2);
  short* WpT  = (short*)alloc(E * 3072 * 2);
  short* cat  = (short*)alloc(12 * NS * E * 2);      // head-major [h][4096][768]; aliases partB later

  // ---- overlay region R: attention pool, then post-attention buffers ----
  char* Rp = base + off;
  const size_t R_size = (ws_size > off) ? (ws_size - off) : 0;

  const size_t per_h = 3 * (NS * E * 2) + 4 * S * S * 2;
  static const int Gs[5] = {6, 4, 3, 2, 1};
  int G = 1;
  for (int i = 0; i < 5; i++)
    if ((size_t)Gs[i] * per_h <= R_size) { G = Gs[i]; break; }

  short* q_g  = (short*)Rp;
  short* k_g  = q_g + (size_t)G * NS * E;
  short* vT_g = k_g + (size_t)G * NS * E;            // [z*4+n][768][1024]
  short* sc_g = vT_g + (size_t)G * NS * E;           // [z*4+n][1024][1024]

  // post-attention overlay (attention pool dead by then)
  size_t o2 = 0;
  float* partA = (float*)(Rp + o2); o2 += 4 * NS * E * 4;   // c_proj split-K=4 partials
  float* y2_f  = (float*)(Rp + o2); o2 += NS * E * 4;
  short* y2_b  = (short*)(Rp + o2); o2 += NS * E * 2;
  short* h_b   = (short*)(Rp + o2); o2 += NS * 3072 * 2;
  float* partB = (float*)cat;                               // 50.3 MB <= cat (75.5 MB)

  const dim3 tb(32, 8);
  transpose_kernel<<<dim3(24, 24, 12), tb, 0, stream>>>(Wq, Wqkv,         768, 768, (long)(E*E), (long)(3*E*E));
  transpose_kernel<<<dim3(24, 24, 12), tb, 0, stream>>>(Wk, Wqkv + E*E,   768, 768, (long)(E*E), (long)(3*E*E));
  transpose_kernel<<<dim3(24, 24, 12), tb, 0, stream>>>(Wv, Wqkv + 2*E*E, 768, 768, (long)(E*E), (long)(3*E*E));
  transpose_kernel<<<dim3(24, 288, 1), tb, 0, stream>>>(Wc, WcT, 9216, 768, 0, 0);
  transpose_kernel<<<dim3(96, 24, 1),  tb, 0, stream>>>(Wfc, WfcT, 768, 3072, 0, 0);
  transpose_kernel<<<dim3(24, 96, 1),  tb, 0, stream>>>(Wp, WpT, 3072, 768, 0, 0);

  ln_kernel<<<4096, 256, 0, stream>>>(inputs, g1, b1, x_f, x_b);

  const float sca = 0.03608439182435161f;  // 1/sqrt(768)
  for (int h0 = 0; h0 < 12; h0 += G) {
    {  // merged QKV: N = 2304 per head; grid.x = m (32, XCD-aligned)
      GP p{};
      p.A = x_b; p.lda = 768; p.a_bs = 0;
      p.B = Wqkv + (size_t)h0 * 3 * E * E; p.ldb = 768; p.b_bs = (long)(3 * E * E);
      p.bias0 = bq; p.bias1 = bk; p.bias2 = bv; p.zoff = h0;
      p.C0 = q_g; p.C1 = k_g; p.C2 = vT_g; p.c_zs = (long)(NS * E);
      p.ldc = 768; p.zmod = 1;
      p.K = 768; p.alpha = 1.0f;
      gemm_qkv<<<dim3(32, 18, G), 256, 0, stream>>>(p);
    }
    {  // scores = q k^T / sqrt(E)
      GP p{};
      p.A = q_g; p.lda = 768; p.a_bs = (long)(S * E);
      p.B = k_g; p.ldb = 768; p.b_bs = (long)(S * E);
      p.C0 = sc_g; p.ldc = 1024; p.zmod = 1; p.cz0 = 0; p.cz1 = (long)(S * S);
      p.K = 768; p.alpha = sca;
      gemm_sco<<<dim3(8, 8, 4 * G), 256, 0, stream>>>(p);
    }
    softmax_kernel<<<4 * G * 1024, 256, 0, stream>>>(sc_g);
    {  // heads = attn @ v -> cat[h][4096][768]
      GP p{};
      p.A = sc_g; p.lda = 1024; p.a_bs = (long)(S * S);
      p.B = vT_g; p.ldb = 1024; p.b_bs = (long)(E * S);
      p.C0 = cat + (size_t)h0 * NS * E; p.ldc = 768;
      p.zmod = 4; p.cz0 = (long)(S * E); p.cz1 = (long)(NS * E);
      p.K = 1024; p.alpha = 1.0f;
      gemm_pv<<<dim3(8, 6, 4 * G), 256, 0, stream>>>(p);
    }
  }

  {  // c_proj split-K=4 (kchunk = 2304 = 3 heads) over head-major cat
    GP p{};
    p.A = cat; p.lda = 768; p.a_kh = 768; p.a_hs = (long)(NS * E);
    p.B = WcT; p.ldb = 9216;
    p.Cf = partA; p.ldc = 768; p.c_zs = (long)(NS * E); p.zmod = 1;
    p.K = 9216; p.kchunk = 2304; p.alpha = 1.0f;
    gemm_cproj<<<dim3(32, 6, 4), 256, 0, stream>>>(p);
  }
  // y = sum(partA) + bc + x_f; y2 = LN(y)  (fused; y never materialized)
  reduce_ln_kernel<<<4096, 256, 0, stream>>>(partA, (long)(NS * E), 4, bc, x_f,
                                             g2, b2, y2_f, y2_b);

  {  // fc + exact gelu
    GP p{};
    p.A = y2_b; p.lda = 768;
    p.B = WfcT; p.ldb = 768;
    p.bias0 = bfc; p.C0 = h_b; p.ldc = 3072; p.zmod = 1;
    p.K = 768; p.alpha = 1.0f;
    gemm_fc<<<dim3(32, 24, 1), 256, 0, stream>>>(p);
  }
  {  // proj split-K=4
    GP p{};
    p.A = h_b; p.lda = 3072;
    p.B = WpT; p.ldb = 3072;
    p.Cf = partB; p.ldc = 768; p.c_zs = (long)(NS * E); p.zmod = 1;
    p.K = 3072; p.kchunk = 768; p.alpha = 1.0f;
    gemm_mproj<<<dim3(32, 6, 4), 256, 0, stream>>>(p);
  }
  reduce_kernel<<<3072, 256, 0, stream>>>(partB, (long)(NS * E), 4, bp, y2_f, out);
}